// Round 2
// baseline (225.154 us; speedup 1.0000x reference)
//
#include <hip/hip_runtime.h>
#include <hip/hip_bf16.h>

typedef __bf16 bf16x8_t __attribute__((ext_vector_type(8)));
typedef float floatx4_t __attribute__((ext_vector_type(4)));

#define H 128
#define BATCH 256
#define SEQ 1024
#define NROWS_TOTAL (BATCH * SEQ)            // 262144 rows of x
#define STEP_ELEMS 33521664.0f               // 256*1023*128

// ws layout: [0, 32768)      : Dpack, bf16, MFMA-B-fragment order [kt][n][lane][j]
//            [32768, 32776)  : accum[0]=step_sum, accum[1]=l2_sum
//            [65536, 131072) : T = A*A, fp32 row-major
//
// Algebra: f(y)=y@C.T is linear, so RK4 collapses to y1 = y·(I + D),
// D = A + A^2/2 + A^3/6 + A^4/24, A = C^T (truncated expm). Main pass is one
// streaming GEMM P = y·D (bf16 MFMA on the small correction; residual (y-x1)
// kept in exact fp32), reading x exactly once: 134 MB -> HBM floor ~20 us.
// v3: residual path through per-wave LDS P-tile (vector loads, no scalar
// gathers). Separate finalize kernel (v2's fused last-block finalize removed —
// suspected interaction with harness replay).

// ---- prep stage 1: T = A*A (A = C^T), plus l2 term and accumulator init ----
__global__ __launch_bounds__(256) void prep_p1(const float* __restrict__ C,
                                               float* __restrict__ T,
                                               float* __restrict__ accum) {
  int e = blockIdx.x * 256 + threadIdx.x;    // 64 WGs * 256 = 16384 elements
  int i = e >> 7, j = e & 127;
  const float* Ci = C + i;                   // C[k][i], stride H — wave-broadcast
  const float* Cj = C + j * H;               // own row, stride 1
  float s = 0.f;
  #pragma unroll 8
  for (int k = 0; k < H; k++) s += Ci[k * H] * Cj[k];
  T[e] = s;

  if (blockIdx.x == 0) {
    float l2 = 0.f;
    for (int q = threadIdx.x; q < H * H; q += 256) {
      float c = C[q], c2 = c * c;
      l2 += c2 * c2;                         // sum C^4
    }
    #pragma unroll
    for (int off = 32; off > 0; off >>= 1) l2 += __shfl_down(l2, off);
    __shared__ float red[4];
    if ((threadIdx.x & 63) == 0) red[threadIdx.x >> 6] = l2;
    __syncthreads();
    if (threadIdx.x == 0) {
      accum[0] = 0.f;
      accum[1] = red[0] + red[1] + red[2] + red[3];
    }
  }
}

// ---- prep stage 2: D = A + T/2 + (T*A)/6 + (T*T)/24, packed to MFMA B-frag layout ----
__global__ __launch_bounds__(256) void prep_p2(const float* __restrict__ C,
                                               const float* __restrict__ T,
                                               __bf16* __restrict__ Dpack) {
  int e = blockIdx.x * 256 + threadIdx.x;
  int i = e >> 7, j = e & 127;
  const float* Ti = T + i * H;               // wave-broadcast row
  const float* Cj = C + j * H;               // own row
  const float* Tj = T + j;                   // column — L2-resident
  float s3 = 0.f, s4 = 0.f;
  #pragma unroll 8
  for (int k = 0; k < H; k++) {
    float t = Ti[k];
    s3 += t * Cj[k];
    s4 += t * Tj[k * H];
  }
  float d = C[j * H + i] + 0.5f * Ti[j] + s3 * (1.f / 6.f) + s4 * (1.f / 24.f);
  // pack: frag(kt,n), lane lanep, elem je holds D[kt*32 + (lanep>>4)*8 + je][n*16 + (lanep&15)]
  int kt = i >> 5, lq = (i >> 3) & 3, je = i & 7;
  int n = j >> 4, mm = j & 15;
  int lanep = lq * 16 + mm;
  Dpack[(size_t)(((kt * 8 + n) * 64 + lanep) * 8 + je)] = (__bf16)d;
}

// ---- main streaming pass: P = y*D via MFMA, residual + square + reduce ----
__global__ __launch_bounds__(256, 2) void sindy_main(const float* __restrict__ x,
                                                     const __bf16* __restrict__ Dpack,
                                                     float* __restrict__ accum) {
  // per-wave P tile: 16 rows x 128 cols, +4 pad keeps 16B alignment and
  // limits ds_read_b128 conflicts to ~4-way (cheap per m136)
  __shared__ float P[4][16][132];

  int lane = threadIdx.x & 63;
  int wave = threadIdx.x >> 6;
  int m = lane & 15, quad = lane >> 4;
  int rrow = (threadIdx.x >> 2) & 15;        // residual row within wave strip
  int cbase = (threadIdx.x & 3) << 5;        // residual col base: 0/32/64/96

  // register-resident B fragments (32 frags x 16B = 128 VGPRs), coalesced load
  bf16x8_t bfr[32];
  const bf16x8_t* Dp = (const bf16x8_t*)Dpack;
  #pragma unroll
  for (int f = 0; f < 32; f++) bfr[f] = Dp[f * 64 + lane];

  float lsum = 0.f;

  for (int tile = blockIdx.x; tile < 4096; tile += gridDim.x) {
    int b = tile >> 4;
    int ts = (tile & 15) << 6;               // s-base of 64-row tile
    int gb = b << 10;

    // A fragments: row sA = ts + wave*16 + m, k = kt*32 + quad*8 + j
    int sA = ts + (wave << 4) + m;
    const float* rp = x + (size_t)(gb + sA) * H + (quad << 3);
    bf16x8_t af[4];
    #pragma unroll
    for (int kt = 0; kt < 4; kt++) {
      floatx4_t u = *(const floatx4_t*)(rp + kt * 32);
      floatx4_t v = *(const floatx4_t*)(rp + kt * 32 + 4);
      bf16x8_t a;
      a[0] = (__bf16)u[0]; a[1] = (__bf16)u[1]; a[2] = (__bf16)u[2]; a[3] = (__bf16)u[3];
      a[4] = (__bf16)v[0]; a[5] = (__bf16)v[1]; a[6] = (__bf16)v[2]; a[7] = (__bf16)v[3];
      af[kt] = a;
    }

    floatx4_t acc[8];
    #pragma unroll
    for (int n = 0; n < 8; n++) acc[n] = (floatx4_t){0.f, 0.f, 0.f, 0.f};
    #pragma unroll
    for (int kt = 0; kt < 4; kt++)
      #pragma unroll
      for (int n = 0; n < 8; n++)
        acc[n] = __builtin_amdgcn_mfma_f32_16x16x32_bf16(af[kt], bfr[kt * 8 + n], acc[n], 0, 0, 0);

    // spill acc -> LDS P (C/D layout: row = quad*4+i2, col = n*16+m).
    // Each wave writes/reads only its own strip -> no __syncthreads; the
    // compiler orders same-wave ds_write->ds_read via lgkmcnt.
    #pragma unroll
    for (int n = 0; n < 8; n++)
      #pragma unroll
      for (int i2 = 0; i2 < 4; i2++)
        P[wave][(quad << 2) + i2][(n << 4) + m] = acc[n][i2];

    // residual, vectorized: thread owns 32 consecutive cols of one row.
    // y/x1 re-reads are L1/L2 hits (rows just fetched for the A fragments).
    int srow = ts + (wave << 4) + rrow;
    if (srow <= SEQ - 2) {
      const float* yp = x + (size_t)(gb + srow) * H + cbase;
      const float* pP = &P[wave][rrow][cbase];
      #pragma unroll
      for (int i = 0; i < 8; i++) {
        floatx4_t yv = *(const floatx4_t*)(yp + 4 * i);
        floatx4_t xv = *(const floatx4_t*)(yp + H + 4 * i);   // row srow+1, same batch
        floatx4_t pv = *(const floatx4_t*)(pP + 4 * i);
        #pragma unroll
        for (int c = 0; c < 4; c++) {
          float r = (yv[c] - xv[c]) + pv[c];
          lsum += r * r;
        }
      }
    }
  }

  #pragma unroll
  for (int off = 32; off > 0; off >>= 1) lsum += __shfl_down(lsum, off);
  __shared__ float red[4];
  if (lane == 0) red[wave] = lsum;
  __syncthreads();
  if (threadIdx.x == 0) atomicAdd(accum, red[0] + red[1] + red[2] + red[3]);
}

__global__ void finalize_kernel(const float* __restrict__ accum, float* __restrict__ out) {
  out[0] = accum[0] * (1.0f / STEP_ELEMS) + 0.001f * accum[1] * (1.0f / 16384.0f);
}

extern "C" void kernel_launch(void* const* d_in, const int* in_sizes, int n_in,
                              void* d_out, int out_size, void* d_ws, size_t ws_size,
                              hipStream_t stream) {
  const float* x = (const float*)d_in[0];
  const float* C = (const float*)d_in[1];
  __bf16* Dpack = (__bf16*)d_ws;
  float* accum = (float*)((char*)d_ws + 32768);
  float* T = (float*)((char*)d_ws + 65536);
  float* out = (float*)d_out;

  prep_p1<<<64, 256, 0, stream>>>(C, T, accum);
  prep_p2<<<64, 256, 0, stream>>>(C, T, Dpack);
  sindy_main<<<512, 256, 0, stream>>>(x, Dpack, accum);
  finalize_kernel<<<1, 1, 0, stream>>>(accum, out);
}

// Round 3
// 212.444 us; speedup vs baseline: 1.0598x; 1.0598x over previous
//
#include <hip/hip_runtime.h>
#include <hip/hip_bf16.h>

typedef __bf16 bf16x8_t __attribute__((ext_vector_type(8)));
typedef float floatx4_t __attribute__((ext_vector_type(4)));

#define H 128
#define BATCH 256
#define SEQ 1024
#define NROWS_TOTAL (BATCH * SEQ)            // 262144 rows of x
#define STEP_ELEMS 33521664.0f               // 256*1023*128

// ws layout: [0, 32768)      : Dpack, bf16, MFMA-B-fragment order [kt][n][lane][j]
//            [32768, 32776)  : accum[0]=step_sum, accum[1]=l2_sum
//            [65536, 131072) : T = A*A, fp32 row-major
//
// Algebra: f(y)=y@C.T is linear, so RK4 collapses to y1 = y·(I + D),
// D = A + A^2/2 + A^3/6 + A^4/24, A = C^T (truncated expm). Main pass is one
// streaming GEMM P = y·D (bf16 MFMA on the small correction; residual (y-x1)
// kept in exact fp32), reading x exactly once: 134 MB -> HBM floor ~20 us.
// v4: occupancy attack. v1/v3 held all of D in regs (128 VGPR/lane -> 2
// waves/SIMD, latency-bound at ~2.4 TB/s). Now: 512-thread blocks, n-split
// across 8 waves (B-slice = 16 VGPR/wave), x-tile staged once in LDS as bf16
// A-fragments. Target 4 waves/SIMD.

// ---- prep stage 1: T = A*A (A = C^T), plus l2 term and accumulator init ----
__global__ __launch_bounds__(256) void prep_p1(const float* __restrict__ C,
                                               float* __restrict__ T,
                                               float* __restrict__ accum) {
  int e = blockIdx.x * 256 + threadIdx.x;    // 64 WGs * 256 = 16384 elements
  int i = e >> 7, j = e & 127;
  const float* Ci = C + i;                   // C[k][i], stride H — wave-broadcast
  const float* Cj = C + j * H;               // own row, stride 1
  float s = 0.f;
  #pragma unroll 8
  for (int k = 0; k < H; k++) s += Ci[k * H] * Cj[k];
  T[e] = s;

  if (blockIdx.x == 0) {
    float l2 = 0.f;
    for (int q = threadIdx.x; q < H * H; q += 256) {
      float c = C[q], c2 = c * c;
      l2 += c2 * c2;                         // sum C^4
    }
    #pragma unroll
    for (int off = 32; off > 0; off >>= 1) l2 += __shfl_down(l2, off);
    __shared__ float red[4];
    if ((threadIdx.x & 63) == 0) red[threadIdx.x >> 6] = l2;
    __syncthreads();
    if (threadIdx.x == 0) {
      accum[0] = 0.f;
      accum[1] = red[0] + red[1] + red[2] + red[3];
    }
  }
}

// ---- prep stage 2: D = A + T/2 + (T*A)/6 + (T*T)/24, packed to MFMA B-frag layout ----
__global__ __launch_bounds__(256) void prep_p2(const float* __restrict__ C,
                                               const float* __restrict__ T,
                                               __bf16* __restrict__ Dpack) {
  int e = blockIdx.x * 256 + threadIdx.x;
  int i = e >> 7, j = e & 127;
  const float* Ti = T + i * H;               // wave-broadcast row
  const float* Cj = C + j * H;               // own row
  const float* Tj = T + j;                   // column — L2-resident
  float s3 = 0.f, s4 = 0.f;
  #pragma unroll 8
  for (int k = 0; k < H; k++) {
    float t = Ti[k];
    s3 += t * Cj[k];
    s4 += t * Tj[k * H];
  }
  float d = C[j * H + i] + 0.5f * Ti[j] + s3 * (1.f / 6.f) + s4 * (1.f / 24.f);
  // pack: frag(kt,n), lane lanep, elem je holds D[kt*32 + (lanep>>4)*8 + je][n*16 + (lanep&15)]
  int kt = i >> 5, lq = (i >> 3) & 3, je = i & 7;
  int n = j >> 4, mm = j & 15;
  int lanep = lq * 16 + mm;
  Dpack[(size_t)(((kt * 8 + n) * 64 + lanep) * 8 + je)] = (__bf16)d;
}

// ---- main streaming pass: P = y*D via MFMA, residual + square + reduce ----
// 512 threads = 8 waves; wave w owns output columns [16w, 16w+16).
__global__ __launch_bounds__(512, 4) void sindy_main(const float* __restrict__ x,
                                                     const __bf16* __restrict__ Dpack,
                                                     float* __restrict__ accum) {
  // x-tile as bf16 MFMA-A fragments: [rowg][kt][lane][j], 16 KB, linear
  // per-lane frag addressing -> conflict-free b128 LDS traffic
  __shared__ __align__(16) __bf16 Atile[4][4][64][8];

  int tid = threadIdx.x;
  int lane = tid & 63;
  int wave = tid >> 6;                       // 0..7 = B n-frag index
  int m = lane & 15, quad = lane >> 4;
  int col = (wave << 4) + m;                 // output column of this lane

  // B fragments for this wave's 16-col strip: 4 frags = 16 VGPRs
  bf16x8_t breg[4];
  const bf16x8_t* Dp = (const bf16x8_t*)Dpack;
  #pragma unroll
  for (int kt = 0; kt < 4; kt++) breg[kt] = Dp[(kt * 8 + wave) * 64 + lane];

  // staging coords: thread loads row (tid>>3), 16-col group (tid&7)
  int srow_st = tid >> 3;                    // 0..63
  int g2 = tid & 7;
  int rowg_st = srow_st >> 4, m_st = srow_st & 15;
  int kt_st = g2 >> 1;
  int quad0 = (g2 & 1) << 1;                 // 0 or 2

  float lsum = 0.f;

  for (int tile = blockIdx.x; tile < 4096; tile += gridDim.x) {
    int b = tile >> 4;
    int ts = (tile & 15) << 6;               // s-base of 64-row tile
    int gb = b << 10;

    // ---- stage: 64x128 fp32 -> bf16 A-frags in LDS (each elem cvt'd once) ----
    {
      const float* src = x + (size_t)(gb + ts + srow_st) * H + (g2 << 4);
      floatx4_t u0 = *(const floatx4_t*)(src);
      floatx4_t u1 = *(const floatx4_t*)(src + 4);
      floatx4_t u2 = *(const floatx4_t*)(src + 8);
      floatx4_t u3 = *(const floatx4_t*)(src + 12);
      bf16x8_t f0, f1;
      f0[0] = (__bf16)u0[0]; f0[1] = (__bf16)u0[1]; f0[2] = (__bf16)u0[2]; f0[3] = (__bf16)u0[3];
      f0[4] = (__bf16)u1[0]; f0[5] = (__bf16)u1[1]; f0[6] = (__bf16)u1[2]; f0[7] = (__bf16)u1[3];
      f1[0] = (__bf16)u2[0]; f1[1] = (__bf16)u2[1]; f1[2] = (__bf16)u2[2]; f1[3] = (__bf16)u2[3];
      f1[4] = (__bf16)u3[0]; f1[5] = (__bf16)u3[1]; f1[6] = (__bf16)u3[2]; f1[7] = (__bf16)u3[3];
      *(bf16x8_t*)&Atile[rowg_st][kt_st][(quad0 + 0) * 16 + m_st][0] = f0;
      *(bf16x8_t*)&Atile[rowg_st][kt_st][(quad0 + 1) * 16 + m_st][0] = f1;
    }
    __syncthreads();

    // ---- MFMA: this wave computes P[all 64 rows][its 16 cols] ----
    floatx4_t acc[4];                        // [rowg]
    #pragma unroll
    for (int rg = 0; rg < 4; rg++) acc[rg] = (floatx4_t){0.f, 0.f, 0.f, 0.f};
    #pragma unroll
    for (int kt = 0; kt < 4; kt++) {
      bf16x8_t af[4];
      #pragma unroll
      for (int rg = 0; rg < 4; rg++) af[rg] = *(const bf16x8_t*)&Atile[rg][kt][lane][0];
      #pragma unroll
      for (int rg = 0; rg < 4; rg++)
        acc[rg] = __builtin_amdgcn_mfma_f32_16x16x32_bf16(af[rg], breg[kt], acc[rg], 0, 0, 0);
    }

    // ---- residual: exact fp32 from global (L1/L2 hits on just-fetched rows).
    // C/D layout: row = rowg*16 + quad*4 + i2, col = wave*16 + m.
    // x1[s] == y[s+1] -> 5 row-loads cover 4 residual rows.
    #pragma unroll
    for (int rg = 0; rg < 4; rg++) {
      int sr = ts + (rg << 4) + (quad << 2);
      const float* yp = x + (size_t)(gb + sr) * H + col;
      float yv[5];
      #pragma unroll
      for (int i2 = 0; i2 < 4; i2++) yv[i2] = yp[(size_t)i2 * H];
      size_t r4 = (size_t)(gb + sr) + 4;     // row sr+4: x1 of i2=3
      if (r4 > (size_t)(NROWS_TOTAL - 1)) r4 = (size_t)(NROWS_TOTAL - 1);
      yv[4] = x[r4 * H + col];
      #pragma unroll
      for (int i2 = 0; i2 < 4; i2++) {
        if (sr + i2 <= SEQ - 2) {
          float rr = (yv[i2] - yv[i2 + 1]) + acc[rg][i2];
          lsum += rr * rr;
        }
      }
    }
    __syncthreads();                         // protect Atile before next stage
  }

  #pragma unroll
  for (int off = 32; off > 0; off >>= 1) lsum += __shfl_down(lsum, off);
  __shared__ float red[8];
  if (lane == 0) red[wave] = lsum;
  __syncthreads();
  if (tid == 0) {
    float s = red[0] + red[1] + red[2] + red[3] + red[4] + red[5] + red[6] + red[7];
    atomicAdd(accum, s);
  }
}

__global__ void finalize_kernel(const float* __restrict__ accum, float* __restrict__ out) {
  out[0] = accum[0] * (1.0f / STEP_ELEMS) + 0.001f * accum[1] * (1.0f / 16384.0f);
}

extern "C" void kernel_launch(void* const* d_in, const int* in_sizes, int n_in,
                              void* d_out, int out_size, void* d_ws, size_t ws_size,
                              hipStream_t stream) {
  const float* x = (const float*)d_in[0];
  const float* C = (const float*)d_in[1];
  __bf16* Dpack = (__bf16*)d_ws;
  float* accum = (float*)((char*)d_ws + 32768);
  float* T = (float*)((char*)d_ws + 65536);
  float* out = (float*)d_out;

  prep_p1<<<64, 256, 0, stream>>>(C, T, accum);
  prep_p2<<<64, 256, 0, stream>>>(C, T, Dpack);
  sindy_main<<<1024, 512, 0, stream>>>(x, Dpack, accum);
  finalize_kernel<<<1, 1, 0, stream>>>(accum, out);
}